// Round 3
// baseline (269.828 us; speedup 1.0000x reference)
//
#include <hip/hip_runtime.h>

// (B,T,S,D) = (4,2048,4,1024); all tensors float32.
// Round-3 experiment: force memory-level parallelism. All prior builds (VGPR
// 32-40) physically could not keep >~2 loads in flight per wave; every variant
// (schedules, nt vs temporal stores) landed at 88-95us = 5.6 B/cyc/CU, exactly
// half the copy ubench's 10 B/cyc. Two-phase structure: issue ALL 20 tile
// loads into named registers (20KB in flight/wave), sched_barrier(0) so the
// scheduler cannot sink loads into compute, then 4x compute+store.
// __launch_bounds__(256,4): <=128 VGPR, 4 blocks/CU, 16 waves x 20KB = 320KB
// outstanding per CU (latency-BW product needs only ~9KB).
constexpr int Bc = 4;
constexpr int Tc = 2048;
constexpr int Sc = 4;
constexpr int Dc = 1024;
constexpr int BT = Bc * Tc;                 // 8192
constexpr int SD = Sc * Dc;                 // 4096
constexpr int SINKHORN_ITERS = 20;
constexpr int NBLK = 2048;
constexpr int XT = NBLK * SD;               // x/out element stride between tiles
constexpr int LT = NBLK * Dc;               // lo element stride between tiles

typedef float vfloat4 __attribute__((ext_vector_type(4)));

__device__ __forceinline__ float uniform_f(float v) {
    return __uint_as_float(__builtin_amdgcn_readfirstlane(__float_as_uint(v)));
}

__global__ __launch_bounds__(256, 4) void fused_kernel(
        const float* __restrict__ x,
        const float* __restrict__ lo,
        const float* __restrict__ Hres,
        const float* __restrict__ Hpos,
        const float* __restrict__ alpha_res,
        const float* __restrict__ alpha_pos,
        const float* __restrict__ bias_res,
        const float* __restrict__ bias_pos,
        float* __restrict__ out) {
    __shared__ float s_aH[16];     // s_aH[r*4+s] = alpha_res * P[s][r]
    __shared__ float s_hp[4];      // alpha_pos * H_pos[r]
    __shared__ vfloat4 s_cb[4 * 256];  // [r][tid]: bias_res+bias_pos, 16 KB

    const int tid = threadIdx.x;
    const int d0 = tid << 2;
    const int bt0 = blockIdx.x;

    // ---- stage combined bias into LDS ----
#pragma unroll
    for (int r = 0; r < 4; ++r) {
        const vfloat4 br = *reinterpret_cast<const vfloat4*>(bias_res + r * Dc + d0);
        const vfloat4 bp = *reinterpret_cast<const vfloat4*>(bias_pos + r * Dc + d0);
        s_cb[r * 256 + tid] = br + bp;
    }

    // ---- Sinkhorn on H (4x4), first 16 lanes of wave 0 ----
    if (tid < 16) {
        const int i = tid >> 2;     // row
        const int j = tid & 3;      // col
        const float h = Hres[i * 4 + j];
        float m = fmaxf(h, __shfl_xor(h, 1));
        m = fmaxf(m, __shfl_xor(m, 2));
        float P = __expf(h - m);
        for (int it = 0; it < SINKHORN_ITERS; ++it) {
            float s = P + __shfl_xor(P, 1);
            s += __shfl_xor(s, 2);
            P *= __builtin_amdgcn_rcpf(s + 1e-8f);   // ~1e-5 rel err, fine
            float c = P + __shfl_xor(P, 4);
            c += __shfl_xor(c, 8);
            P *= __builtin_amdgcn_rcpf(c + 1e-8f);
        }
        // einsum 'btsd,sr->btrd': out stream r contracts x stream s with P[s][r].
        s_aH[j * 4 + i] = alpha_res[0] * P;
        if (i == 0) s_hp[j] = alpha_pos[0] * Hpos[j];
    }
    __syncthreads();   // conservative vmcnt(0) drain happens HERE, before the big loads

    // ---- wave-uniform coefficients -> SGPRs ----
    float aH[4][4];
    float hp[4];
#pragma unroll
    for (int r = 0; r < 4; ++r) {
#pragma unroll
        for (int s = 0; s < 4; ++s) aH[r][s] = uniform_f(s_aH[r * 4 + s]);
        hp[r] = uniform_f(s_hp[r]);
    }

    // ---- Phase 1: issue ALL 20 loads (4 tiles x (4 x-rows + 1 lo row)) ----
    const float* xb = x + bt0 * SD + d0;
    const float* lb = lo + bt0 * Dc + d0;
    vfloat4 t0s0 = *reinterpret_cast<const vfloat4*>(xb + 0 * XT);
    vfloat4 t0s1 = *reinterpret_cast<const vfloat4*>(xb + 0 * XT + Dc);
    vfloat4 t0s2 = *reinterpret_cast<const vfloat4*>(xb + 0 * XT + 2 * Dc);
    vfloat4 t0s3 = *reinterpret_cast<const vfloat4*>(xb + 0 * XT + 3 * Dc);
    vfloat4 t0l  = *reinterpret_cast<const vfloat4*>(lb + 0 * LT);
    vfloat4 t1s0 = *reinterpret_cast<const vfloat4*>(xb + 1 * XT);
    vfloat4 t1s1 = *reinterpret_cast<const vfloat4*>(xb + 1 * XT + Dc);
    vfloat4 t1s2 = *reinterpret_cast<const vfloat4*>(xb + 1 * XT + 2 * Dc);
    vfloat4 t1s3 = *reinterpret_cast<const vfloat4*>(xb + 1 * XT + 3 * Dc);
    vfloat4 t1l  = *reinterpret_cast<const vfloat4*>(lb + 1 * LT);
    vfloat4 t2s0 = *reinterpret_cast<const vfloat4*>(xb + 2 * XT);
    vfloat4 t2s1 = *reinterpret_cast<const vfloat4*>(xb + 2 * XT + Dc);
    vfloat4 t2s2 = *reinterpret_cast<const vfloat4*>(xb + 2 * XT + 2 * Dc);
    vfloat4 t2s3 = *reinterpret_cast<const vfloat4*>(xb + 2 * XT + 3 * Dc);
    vfloat4 t2l  = *reinterpret_cast<const vfloat4*>(lb + 2 * LT);
    vfloat4 t3s0 = *reinterpret_cast<const vfloat4*>(xb + 3 * XT);
    vfloat4 t3s1 = *reinterpret_cast<const vfloat4*>(xb + 3 * XT + Dc);
    vfloat4 t3s2 = *reinterpret_cast<const vfloat4*>(xb + 3 * XT + 2 * Dc);
    vfloat4 t3s3 = *reinterpret_cast<const vfloat4*>(xb + 3 * XT + 3 * Dc);
    vfloat4 t3l  = *reinterpret_cast<const vfloat4*>(lb + 3 * LT);

    // Forbid the scheduler from sinking any load past this point (keeps all 20
    // in flight; compiler still inserts counted vmcnt waits at each use).
    __builtin_amdgcn_sched_barrier(0);

    // ---- Phase 2: compute + store, tile by tile (oldest loads first) ----
    auto compute_store = [&](int it, vfloat4 x0, vfloat4 x1, vfloat4 x2,
                             vfloat4 x3, vfloat4 lv) {
        float* op = out + bt0 * SD + it * XT + d0;
        vfloat4 xs[4] = {x0, x1, x2, x3};   // static indexing only -> registers
#pragma unroll
        for (int r = 0; r < 4; ++r) {
            const vfloat4 cb = s_cb[r * 256 + tid];
            vfloat4 acc;
#pragma unroll
            for (int j = 0; j < 4; ++j)
                acc[j] = fmaf(lv[j], hp[r], xs[r][j] + cb[j]);
#pragma unroll
            for (int s = 0; s < 4; ++s)
#pragma unroll
                for (int j = 0; j < 4; ++j)
                    acc[j] = fmaf(xs[s][j], aH[r][s], acc[j]);
            *reinterpret_cast<vfloat4*>(op + r * Dc) = acc;
        }
    };

    compute_store(0, t0s0, t0s1, t0s2, t0s3, t0l);
    compute_store(1, t1s0, t1s1, t1s2, t1s3, t1l);
    compute_store(2, t2s0, t2s1, t2s2, t2s3, t2l);
    compute_store(3, t3s0, t3s1, t3s2, t3s3, t3l);
}

extern "C" void kernel_launch(void* const* d_in, const int* in_sizes, int n_in,
                              void* d_out, int out_size, void* d_ws, size_t ws_size,
                              hipStream_t stream) {
    const float* x         = (const float*)d_in[0];
    const float* layer_out = (const float*)d_in[1];
    const float* H_res     = (const float*)d_in[2];
    const float* H_pos     = (const float*)d_in[3];
    const float* alpha_res = (const float*)d_in[4];
    const float* alpha_pos = (const float*)d_in[5];
    const float* bias_res  = (const float*)d_in[6];
    const float* bias_pos  = (const float*)d_in[7];
    float* out = (float*)d_out;

    fused_kernel<<<NBLK, 256, 0, stream>>>(x, layer_out, H_res, H_pos,
                                           alpha_res, alpha_pos,
                                           bias_res, bias_pos, out);
}

// Round 4
// 264.190 us; speedup vs baseline: 1.0213x; 1.0213x over previous
//
#include <hip/hip_runtime.h>

// (B,T,S,D) = (4,2048,4,1024); all tensors float32.
// Round-4: TLP experiment. 8192 blocks x 1 bt-tile (was 2048 x 4): 32 queued
// blocks/CU -> retire-and-replace hides ramp/drain; occupancy counter never
// exceeded 55% on the 2048-block builds and occupancy is the only axis that
// has correlated with perf (R2 occ 55% = 86.6us best; R3 occ 35% = 92us).
// Barrier-free: Sinkhorn computed redundantly per-wave via intra-wave shuffles
// (4x4 matrix replicated per 16-lane group; xor masks 1/2/4/8 stay in-group),
// coefficients broadcast via v_readlane into SGPRs. No LDS, no __syncthreads,
// no vmcnt(0) drain points -> each wave is an independent load->compute->store
// stream. __launch_bounds__(256,8) pins VGPR<=64 for full 8 waves/SIMD.
constexpr int Dc = 1024;
constexpr int SD = 4 * Dc;                  // 4096
constexpr int SINKHORN_ITERS = 20;
constexpr int NBLK = 8192;                  // == B*T; one bt-tile per block

typedef float vfloat4 __attribute__((ext_vector_type(4)));

__device__ __forceinline__ float readlane_f(float v, int lane) {
    return __uint_as_float(__builtin_amdgcn_readlane(__float_as_uint(v), lane));
}

__global__ __launch_bounds__(256, 8) void fused_kernel(
        const float* __restrict__ x,
        const float* __restrict__ lo,
        const float* __restrict__ Hres,
        const float* __restrict__ Hpos,
        const float* __restrict__ alpha_res,
        const float* __restrict__ alpha_pos,
        const float* __restrict__ bias_res,
        const float* __restrict__ bias_pos,
        float* __restrict__ out) {
    const int tid  = threadIdx.x;
    const int lane = tid & 63;
    const int d0   = tid << 2;
    const int bt   = blockIdx.x;

    // ---- issue the streaming loads first (fly during Sinkhorn VALU work) ----
    const float* xp = x + bt * SD + d0;
    const vfloat4 x0 = *reinterpret_cast<const vfloat4*>(xp);
    const vfloat4 x1 = *reinterpret_cast<const vfloat4*>(xp + Dc);
    const vfloat4 x2 = *reinterpret_cast<const vfloat4*>(xp + 2 * Dc);
    const vfloat4 x3 = *reinterpret_cast<const vfloat4*>(xp + 3 * Dc);
    const vfloat4 lv = *reinterpret_cast<const vfloat4*>(lo + bt * Dc + d0);

    // bias (L2-hot 32 KB working set; re-read per block, never reaches HBM)
    vfloat4 cb[4];
#pragma unroll
    for (int r = 0; r < 4; ++r) {
        const vfloat4 br = *reinterpret_cast<const vfloat4*>(bias_res + r * Dc + d0);
        const vfloat4 bp = *reinterpret_cast<const vfloat4*>(bias_pos + r * Dc + d0);
        cb[r] = br + bp;
    }

    // ---- Sinkhorn, redundantly in every 16-lane group (no LDS, no barrier) ----
    // lane l holds P[i][j], i=(l>>2)&3, j=l&3; replicated across the 4 groups.
    const int i = (lane >> 2) & 3;
    const int j = lane & 3;
    const float h   = Hres[i * 4 + j];
    const float hpv = Hpos[j];               // lane r (r<4) holds Hpos[r]
    const float a_res = alpha_res[0];
    const float a_pos = alpha_pos[0];

    float m = fmaxf(h, __shfl_xor(h, 1));
    m = fmaxf(m, __shfl_xor(m, 2));
    float P = __expf(h - m);
#pragma unroll
    for (int it = 0; it < SINKHORN_ITERS; ++it) {
        float s = P + __shfl_xor(P, 1);      // row sum (over j: bits 0,1)
        s += __shfl_xor(s, 2);
        P *= __builtin_amdgcn_rcpf(s + 1e-8f);   // ~1e-5 rel err, fine
        float c = P + __shfl_xor(P, 4);      // col sum (over i: bits 2,3)
        c += __shfl_xor(c, 8);
        P *= __builtin_amdgcn_rcpf(c + 1e-8f);
    }

    // einsum 'btsd,sr->btrd': out stream r contracts x stream s with P[s][r].
    // aH[r][s] = alpha_res * P[s][r]  -> value sits at lane 4*s + r.
    const float aP = a_res * P;
    float aH[4][4], hp[4];
#pragma unroll
    for (int r = 0; r < 4; ++r) {
#pragma unroll
        for (int s = 0; s < 4; ++s) aH[r][s] = readlane_f(aP, 4 * s + r);
        hp[r] = a_pos * readlane_f(hpv, r);
    }

    // ---- compute + store (temporal; R2 showed nt stores are slower) ----
    const vfloat4 xs[4] = {x0, x1, x2, x3};  // static indexing only -> registers
    float* op = out + bt * SD + d0;
#pragma unroll
    for (int r = 0; r < 4; ++r) {
        vfloat4 acc;
#pragma unroll
        for (int jj = 0; jj < 4; ++jj)
            acc[jj] = fmaf(lv[jj], hp[r], xs[r][jj] + cb[r][jj]);
#pragma unroll
        for (int s = 0; s < 4; ++s)
#pragma unroll
            for (int jj = 0; jj < 4; ++jj)
                acc[jj] = fmaf(xs[s][jj], aH[r][s], acc[jj]);
        *reinterpret_cast<vfloat4*>(op + r * Dc) = acc;
    }
}

extern "C" void kernel_launch(void* const* d_in, const int* in_sizes, int n_in,
                              void* d_out, int out_size, void* d_ws, size_t ws_size,
                              hipStream_t stream) {
    const float* x         = (const float*)d_in[0];
    const float* layer_out = (const float*)d_in[1];
    const float* H_res     = (const float*)d_in[2];
    const float* H_pos     = (const float*)d_in[3];
    const float* alpha_res = (const float*)d_in[4];
    const float* alpha_pos = (const float*)d_in[5];
    const float* bias_res  = (const float*)d_in[6];
    const float* bias_pos  = (const float*)d_in[7];
    float* out = (float*)d_out;

    fused_kernel<<<NBLK, 256, 0, stream>>>(x, layer_out, H_res, H_pos,
                                           alpha_res, alpha_pos,
                                           bias_res, bias_pos, out);
}